// Round 10
// baseline (152.637 us; speedup 1.0000x reference)
//
#include <hip/hip_runtime.h>
#include <hip/hip_bf16.h>
#include <cstdint>
#include <cstddef>

#define B_ 2
#define S_ 2048
#define D_ 768
#define H_ 12
#define M_ 64
#define BS_ (B_ * S_)
#define NQKV_ 2304            // 3 * 768 packed output columns
#define NCHUNK_ 80            // compact chunks per bh (sum of ceil((qt+1)/8))
#define TOTCHUNK_ (24 * NCHUNK_)   // 1920
#define QSCALE 0.18033688011f // 0.125 * log2(e): softmax done in exp2 space

typedef __attribute__((ext_vector_type(8))) short bf16x8;
typedef __attribute__((ext_vector_type(4))) short bf16x4;
typedef __attribute__((ext_vector_type(4))) float f32x4;

__device__ __forceinline__ unsigned short f2bu(float f) {
    __hip_bfloat16 h = __float2bfloat16(f);   // RNE
    unsigned short u;
    __builtin_memcpy(&u, &h, 2);
    return u;
}
__device__ __forceinline__ unsigned pack2(float a, float b) {
    return (unsigned)f2bu(a) | ((unsigned)f2bu(b) << 16);
}

// Alias-safe vector load/store (memcpy => char semantics, still b128 ops).
__device__ __forceinline__ bf16x8 ld16(const unsigned short* p) {
    p = (const unsigned short*)__builtin_assume_aligned(p, 16);
    bf16x8 v; __builtin_memcpy(&v, p, 16); return v;
}
__device__ __forceinline__ bf16x4 ld8(const unsigned short* p) {
    p = (const unsigned short*)__builtin_assume_aligned(p, 8);
    bf16x4 v; __builtin_memcpy(&v, p, 8); return v;
}
__device__ __forceinline__ uint4 ld16u(const unsigned short* p) {
    p = (const unsigned short*)__builtin_assume_aligned(p, 16);
    uint4 v; __builtin_memcpy(&v, p, 16); return v;
}
__device__ __forceinline__ void st16(unsigned short* p, uint4 v) {
    p = (unsigned short*)__builtin_assume_aligned(p, 16);
    __builtin_memcpy(p, &v, 16);
}
__device__ __forceinline__ void st8(unsigned short* p, uint2 v) {
    p = (unsigned short*)__builtin_assume_aligned(p, 8);
    __builtin_memcpy(p, &v, 8);
}
__device__ __forceinline__ float4 ldf4(const float* p) {
    p = (const float*)__builtin_assume_aligned(p, 16);
    float4 v; __builtin_memcpy(&v, p, 16); return v;
}
// async global->LDS, 16B per lane; lds base must be wave-uniform.
__device__ __forceinline__ void async16(const unsigned short* g, unsigned short* l) {
    __builtin_amdgcn_global_load_lds(
        (const __attribute__((address_space(1))) void*)g,
        (__attribute__((address_space(3))) void*)l, 16, 0, 0);
}
__device__ __forceinline__ void b82f(uint4 u, float* o) {
    o[0] = __uint_as_float(u.x << 16); o[1] = __uint_as_float(u.x & 0xffff0000u);
    o[2] = __uint_as_float(u.y << 16); o[3] = __uint_as_float(u.y & 0xffff0000u);
    o[4] = __uint_as_float(u.z << 16); o[5] = __uint_as_float(u.z & 0xffff0000u);
    o[6] = __uint_as_float(u.w << 16); o[7] = __uint_as_float(u.w & 0xffff0000u);
}

#define NEG_BIG (-3.0e38f)

// ---------------------------------------------------------------------------
// prep: fused weight packing + x conversion.
// ---------------------------------------------------------------------------
__global__ void prep(const float* __restrict__ WQ, const float* __restrict__ WK,
                     const float* __restrict__ WV, const float* __restrict__ WO,
                     const float* __restrict__ x,
                     unsigned short* __restrict__ WT,
                     unsigned short* __restrict__ WOT,
                     unsigned short* __restrict__ xb)
{
    const int bx = blockIdx.x;
    if (bx < 216) {
        const int xx = bx % 9, yy = bx / 9;
        const int c  = xx * 256 + threadIdx.x;   // 0..2303
        const int k0 = yy * 32;
        const int which = c / D_;
        const int r = c - which * D_;
        const int h = r >> 6, m = r & 63;
        const float* Wsel = (which == 0) ? WQ : (which == 1) ? WK : WV;
        const float* src = Wsel + (size_t)h * D_ * M_ + m;
        unsigned short* dst = WT + (size_t)c * D_ + k0;
        for (int i = 0; i < 32; i += 8) {
            float wv[8];
#pragma unroll
            for (int j = 0; j < 8; j++) wv[j] = src[(size_t)(k0 + i + j) * M_];
            uint4 pu;
            pu.x = pack2(wv[0], wv[1]); pu.y = pack2(wv[2], wv[3]);
            pu.z = pack2(wv[4], wv[5]); pu.w = pack2(wv[6], wv[7]);
            st16(dst + i, pu);
        }
    } else if (bx < 288) {
        const int b2 = bx - 216;
        const int xx = b2 % 3, yy = b2 / 3;
        const int c  = xx * 256 + threadIdx.x;   // output row d, 0..767
        const int k0 = yy * 32;
        unsigned short* dst = WOT + (size_t)c * D_ + k0;
        for (int i = 0; i < 32; i += 8) {
            float wv[8];
#pragma unroll
            for (int j = 0; j < 8; j++) wv[j] = WO[(size_t)(k0 + i + j) * D_ + c];
            uint4 pu;
            pu.x = pack2(wv[0], wv[1]); pu.y = pack2(wv[2], wv[3]);
            pu.z = pack2(wv[4], wv[5]); pu.w = pack2(wv[6], wv[7]);
            st16(dst + i, pu);
        }
    } else {
        const size_t i = ((size_t)(bx - 288) * 256 + threadIdx.x) * 16;
#pragma unroll
        for (int p = 0; p < 2; p++) {
            float4 a0 = ldf4(x + i + p * 8), a1 = ldf4(x + i + p * 8 + 4);
            uint4 u;
            u.x = pack2(a0.x, a0.y); u.y = pack2(a0.z, a0.w);
            u.z = pack2(a1.x, a1.y); u.w = pack2(a1.z, a1.w);
            st16(xb + i + p * 8, u);
        }
    }
}

// ---------------------------------------------------------------------------
// QKV projection GEMM (single-buffer async staging).  Tile 128x96 ->
// grid (32,24) = 768 blocks = EXACTLY 3 blocks/CU (R9: imbalance fix,
// -7.4us total).  LDS 28KB, 3 blocks co-resident.
// Q pre-scaled by 0.125*log2(e)  (softmax runs in exp2 space downstream).
// K and V are emitted in PRE-SWIZZLED physical image layouts so attn_split
// can stage them with pure linear global_load_lds:
//   K: [bh][s][phys 16B block p] holds logical block p^(s&7)
//   V: [bh][tile=s>>7][m][32x 8B granules], pair pp = pl^((m>>1)&7),
//      8B half = (gl&1)^(m&1)  (odd feats half-swapped)
// ---------------------------------------------------------------------------
__global__ __launch_bounds__(256, 2) void qkv_gemm(
    const unsigned short* __restrict__ xb,    // [4096][768] bf16
    const unsigned short* __restrict__ WT,    // [2304][768] bf16
    const float* __restrict__ bQ, const float* __restrict__ bK,
    const float* __restrict__ bV,
    unsigned short* __restrict__ qo, unsigned short* __restrict__ ko,
    unsigned short* __restrict__ vt)
{
    const int row0 = blockIdx.x * 128;
    const int col0 = blockIdx.y * 96;
    const int t = threadIdx.x;
    const int w = t >> 6, lane = t & 63, quad = lane >> 4, l16 = lane & 15;
    const int wrow0 = (w & 1) * 64, wcol0 = (w >> 1) * 48;

    __shared__ unsigned short Alds[128 * 64];   // unpadded, swizzled
    __shared__ unsigned short Blds[96 * 64];

    f32x4 acc[4][3] = {};

    const unsigned short* asrc[4];
    const unsigned short* bsrc[3];
    int ldsoffA[4], ldsoffB[3];
#pragma unroll
    for (int q = 0; q < 4; q++) {
        const int cq = w * 256 + q * 64 + lane;
        const int row = cq >> 3, c = cq & 7;
        const int cs = c ^ (row & 7);
        asrc[q] = xb + (size_t)(row0 + row) * D_ + cs * 8;
        ldsoffA[q] = (w * 256 + q * 64) * 8;   // wave-uniform
    }
#pragma unroll
    for (int q = 0; q < 3; q++) {
        const int cq = w * 192 + q * 64 + lane;
        const int row = cq >> 3, c = cq & 7;
        const int cs = c ^ (row & 7);
        bsrc[q] = WT + (size_t)(col0 + row) * D_ + cs * 8;
        ldsoffB[q] = (w * 192 + q * 64) * 8;   // wave-uniform
    }
    const int swz = (l16 & 7);

    for (int k0 = 0; k0 < D_; k0 += 64) {
#pragma unroll
        for (int q = 0; q < 4; q++) async16(asrc[q] + k0, Alds + ldsoffA[q]);
#pragma unroll
        for (int q = 0; q < 3; q++) async16(bsrc[q] + k0, Blds + ldsoffB[q]);
        __syncthreads();   // drains vmcnt -> DMA landed

        bf16x8 af[4][2], bfm[3][2];
#pragma unroll
        for (int rt = 0; rt < 4; rt++) {
            const int row = wrow0 + rt * 16 + l16;
#pragma unroll
            for (int hh = 0; hh < 2; hh++)
                af[rt][hh] = ld16(&Alds[row * 64 + ((hh * 4 + quad) ^ swz) * 8]);
        }
#pragma unroll
        for (int st = 0; st < 3; st++) {
            const int row = wcol0 + st * 16 + l16;
#pragma unroll
            for (int hh = 0; hh < 2; hh++)
                bfm[st][hh] = ld16(&Blds[row * 64 + ((hh * 4 + quad) ^ swz) * 8]);
        }
#pragma unroll
        for (int rt = 0; rt < 4; rt++)
#pragma unroll
            for (int st = 0; st < 3; st++) {
                acc[rt][st] = __builtin_amdgcn_mfma_f32_16x16x32_bf16(
                    af[rt][0], bfm[st][0], acc[rt][st], 0, 0, 0);
                acc[rt][st] = __builtin_amdgcn_mfma_f32_16x16x32_bf16(
                    af[rt][1], bfm[st][1], acc[rt][st], 0, 0, 0);
            }
        __syncthreads();
    }

    const int which = col0 / D_;            // 96*8 = 768: exact boundaries
    const int colin = col0 - which * D_;

    if (which == 0) {
#pragma unroll
        for (int st = 0; st < 3; st++) {
            const int cl = colin + wcol0 + st * 16 + l16;
            const int h = cl >> 6, m = cl & 63;
            const float bval = bQ[cl];
#pragma unroll
            for (int rt = 0; rt < 4; rt++)
#pragma unroll
                for (int rr = 0; rr < 4; rr++) {
                    const int R = row0 + wrow0 + rt * 16 + quad * 4 + rr;
                    const int bb = R >> 11, s = R & (S_ - 1);
                    qo[(((size_t)bb * H_ + h) * S_ + s) * M_ + m] =
                        f2bu((acc[rt][st][rr] + bval) * QSCALE);
                }
        }
    } else if (which == 1) {
        // K: pre-swizzled 16B blocks: elem (s,m) -> block (m>>3)^(s&7), inner m&7
#pragma unroll
        for (int st = 0; st < 3; st++) {
            const int cl = colin + wcol0 + st * 16 + l16;
            const int h = cl >> 6, m = cl & 63;
            const int blk = m >> 3, inn = m & 7;
            const float bval = bK[cl];
#pragma unroll
            for (int rt = 0; rt < 4; rt++)
#pragma unroll
                for (int rr = 0; rr < 4; rr++) {
                    const int R = row0 + wrow0 + rt * 16 + quad * 4 + rr;
                    const int bb = R >> 11, s = R & (S_ - 1);
                    ko[(((size_t)bb * H_ + h) * S_ + s) * M_ +
                       ((blk ^ (s & 7)) << 3) + inn] =
                        f2bu(acc[rt][st][rr] + bval);
                }
        }
    } else {
        // V: tiled-swizzled image [bh][tile][m][granules]; one st8 = one granule.
#pragma unroll
        for (int st = 0; st < 3; st++) {
            const int cl = colin + wcol0 + st * 16 + l16;
            const int h = cl >> 6, m = cl & 63;
            const float bval = bV[cl];
#pragma unroll
            for (int rt = 0; rt < 4; rt++) {
                const int R0 = row0 + wrow0 + rt * 16 + quad * 4;
                const int bb = R0 >> 11, s0 = R0 & (S_ - 1);
                const int tile = s0 >> 7;
                const int gl = (s0 & 127) >> 2;        // logical granule
                const int pl = gl >> 1, hi = gl & 1;
                const int pp = pl ^ ((m >> 1) & 7);    // phys 16B pair
                const int half = hi ^ (m & 1);         // odd feat: swap halves
                uint2 v;
                v.x = pack2(acc[rt][st][0] + bval, acc[rt][st][1] + bval);
                v.y = pack2(acc[rt][st][2] + bval, acc[rt][st][3] + bval);
                st8(&vt[(((size_t)bb * H_ + h) * 16 + tile) * (M_ * 128)
                        + m * 128 + (pp * 2 + half) * 4], v);
            }
        }
    }
}

// ---------------------------------------------------------------------------
// Split-K causal flash attention, transposed compute space, exp2 softmax
// with STATIC zero max.  PV uses K=16 MFMA so the packed QK output registers
// ARE the B-fragment -- no P LDS round-trip.  Best-measured structure:
// single 32KB buffer, pure linear global_load_lds from PRE-SWIZZLED K/V,
// 4 blocks/CU of cross-block TLP hides the DMA drain.
//
// Round 10: (a) T5 s_setprio(1) around the QK and PV MFMA clusters --
// co-resident blocks sit at different phases, so priority lets the
// MFMA-phase wave preempt staging/softmax issue (verified attn-positive,
// learn_hip m191); (b) nc==1 chunks (qt<8) have the complete row sum
// locally -> normalize and write Z directly, skipping Opart+ml (combine
// then only covers qt>=8).  grid (80, 24).
// ---------------------------------------------------------------------------
__global__ __launch_bounds__(256, 2) void attn_split(
    const unsigned short* __restrict__ Q,   // [B,H,S,M] bf16 (exp2-scaled)
    const unsigned short* __restrict__ Kin, // [B,H,S,M] bf16 (block-swizzled)
    const unsigned short* __restrict__ Vt,  // [B,H,16,M,128] bf16 (tiled image)
    unsigned short* __restrict__ Opart,     // [1920][64][64] bf16
    float* __restrict__ ml,                 // [1920][128] fp32 (l in 2nd half)
    unsigned short* __restrict__ Z)         // [B,S,H*M] bf16 (nc==1 direct)
{
    // XCD-locality + descending-work remap (dispatch order is x-major).
    const int flat = blockIdx.y * NCHUNK_ + blockIdx.x;
    const int bh = flat % 24;                    // XCD = flat%8 = bh%8
    const int xx = (NCHUNK_ - 1) - flat / 24;    // big chunks dispatched first

    int qt, c, nc;
    if (xx < 8)       { qt = xx; c = 0; nc = 1; }
    else if (xx < 24) { int u = xx - 8;  qt = 8  + (u >> 1); c = u & 1;  nc = 2; }
    else if (xx < 48) { int u = xx - 24; qt = 16 + u / 3;    c = u % 3;  nc = 3; }
    else              { int u = xx - 48; qt = 24 + (u >> 2); c = u & 3;  nc = 4; }

    const int ci     = bh * NCHUNK_ + xx;
    const int kbeg   = c * 512;
    const int keyend = min((qt + 1) * 64, kbeg + 512);
    const int iters  = (keyend - kbeg + 127) >> 7;
    const bool lastchunk = (c == nc - 1);

    const int t = threadIdx.x;
    const int wave = t >> 6, lane = t & 63, quad = lane >> 4, l16 = lane & 15;

    const unsigned short* Qb  = Q   + ((size_t)bh * S_ + qt * 64) * M_;
    const unsigned short* Kb  = Kin + (size_t)bh * S_ * M_;
    const unsigned short* Vb  = Vt  + (size_t)bh * M_ * S_;   // tiled image

    // Physical (pre-swizzled) tiles, staged linearly; 32 KB total.
    __shared__ unsigned short Klds[128 * 64];
    __shared__ unsigned short Vlds[64 * 128];

    bf16x8 qf[2];   // B-frag of Q^T
    {
        const unsigned short* qrow = Qb + (size_t)(wave * 16 + l16) * M_;
        qf[0] = ld16(qrow + quad * 8);
        qf[1] = ld16(qrow + 32 + quad * 8);
    }

    // lane-constant swizzled read offsets, hoisted out of all loops
    const int ksw = l16 & 7;
    const int ko0 = (quad ^ ksw) * 8;          // K block quad   (feat 0..31)
    const int ko1 = ((quad + 4) ^ ksw) * 8;    // K block quad+4 (feat 32..63)
    int voff[8];                               // V granule addr per key-block
#pragma unroll
    for (int st = 0; st < 8; st++)
        voff[st] = l16 * 128 + (quad ^ (l16 & 3)) * 4
                 + ((st ^ ((l16 >> 2) & 3)) << 4);

    const int wdst = wave * 64 * 8;            // wave-uniform LDS base (ushorts)

    f32x4 o_acc[4] = {};
    float lrow = 0.f;   // per-lane partial sum of P (static max = 0)

    for (int it = 0; it < iters; it++) {
        __syncthreads();   // prior iteration's LDS reads complete
        const int key0 = kbeg + it * 128;
        const unsigned short* kt = Kb + (size_t)key0 * M_;
        const unsigned short* vtile = Vb + (size_t)(key0 >> 7) * (M_ * 128);
#pragma unroll
        for (int q = 0; q < 4; q++)
            async16(kt + (size_t)(q * 256 + t) * 8, Klds + q * 2048 + wdst);
#pragma unroll
        for (int q = 0; q < 4; q++)
            async16(vtile + (size_t)(q * 256 + t) * 8, Vlds + q * 2048 + wdst);
        __syncthreads();   // drains vmcnt -> DMA landed

        // S^T = K Q^T over 128 keys (8 row strips of 16 keys)
        f32x4 s_acc[8];
        __builtin_amdgcn_s_setprio(1);
#pragma unroll
        for (int st = 0; st < 8; st++) {
            f32x4 z4 = {0.f, 0.f, 0.f, 0.f};
            const unsigned short* krow = &Klds[(st * 16 + l16) * 64];
            bf16x8 k0 = ld16(krow + ko0);
            bf16x8 k1 = ld16(krow + ko1);
            z4 = __builtin_amdgcn_mfma_f32_16x16x32_bf16(k0, qf[0], z4, 0, 0, 0);
            z4 = __builtin_amdgcn_mfma_f32_16x16x32_bf16(k1, qf[1], z4, 0, 0, 0);
            s_acc[st] = z4;   // s_acc[st][r] = S^T[key=st*16+quad*4+r][q=l16]
        }
        __builtin_amdgcn_s_setprio(0);

        if (lastchunk && it == iters - 1) {
            const int keyq = kbeg + it * 128 + quad * 4;
            const int qg = qt * 64 + wave * 16 + l16;
#pragma unroll
            for (int st = 0; st < 8; st++)
#pragma unroll
                for (int r = 0; r < 4; r++)
                    if (keyq + st * 16 + r > qg)
                        s_acc[st][r] = -1e30f;
        }

        // P = exp2(S) (no max subtraction), pack strips directly into the
        // K=16 MFMA B-fragment layout (B[k=quad*4+j][n=l16] == C layout!)
        bf16x4 pkv[8];
#pragma unroll
        for (int st = 0; st < 8; st++) {
            float p0 = exp2f(s_acc[st][0]);
            float p1 = exp2f(s_acc[st][1]);
            float p2 = exp2f(s_acc[st][2]);
            float p3 = exp2f(s_acc[st][3]);
            lrow += (p0 + p1) + (p2 + p3);
            uint2 u;
            u.x = pack2(p0, p1);
            u.y = pack2(p2, p3);
            __builtin_memcpy(&pkv[st], &u, 8);
        }

        // O^T += V^T P^T via 16x16x16 MFMA (P straight from registers)
        __builtin_amdgcn_s_setprio(1);
#pragma unroll
        for (int stf = 0; stf < 4; stf++) {
#pragma unroll
            for (int st = 0; st < 8; st++) {
                bf16x4 va = ld8(&Vlds[stf * 2048 + voff[st]]);
                o_acc[stf] = __builtin_amdgcn_mfma_f32_16x16x16bf16_1k(
                    va, pkv[st], o_acc[stf], 0, 0, 0);
            }
        }
        __builtin_amdgcn_s_setprio(0);
    }

    // reduce l across the 4 quads (columns are per-lane; quads partition keys)
    lrow += __shfl_xor(lrow, 16, 64);
    lrow += __shfl_xor(lrow, 32, 64);

    const int q = wave * 16 + l16;
    if (nc == 1) {
        // complete row: normalize and write Z directly (skip Opart/ml)
        const float invL = 1.0f / lrow;
        const int b = bh / H_, h = bh - b * H_;
        unsigned short* zp =
            Z + ((size_t)b * S_ + qt * 64 + q) * (H_ * M_) + h * M_;
#pragma unroll
        for (int stf = 0; stf < 4; stf++) {
            uint2 u;
            u.x = pack2(o_acc[stf][0] * invL, o_acc[stf][1] * invL);
            u.y = pack2(o_acc[stf][2] * invL, o_acc[stf][3] * invL);
            st8(&zp[stf * 16 + quad * 4], u);
        }
    } else {
        // write unnormalized partials (bf16), O^T -> [q][feat] packed stores
        unsigned short* Op = Opart + (size_t)ci * 4096;
#pragma unroll
        for (int stf = 0; stf < 4; stf++) {
            uint2 u;
            u.x = pack2(o_acc[stf][0], o_acc[stf][1]);
            u.y = pack2(o_acc[stf][2], o_acc[stf][3]);
            st8(&Op[q * 64 + stf * 16 + quad * 4], u);
        }
        if (quad == 0)
            ml[(size_t)ci * 128 + 64 + q] = lrow;
    }
}

// ---------------------------------------------------------------------------
// Combine: merge 2..4 bf16 partials per (bh, qt>=8) into Z [B,S,H*M] bf16.
// (qt<8 are written directly by attn_split.)  Static-max softmax ->
// uniform weights: z = (sum O_c) / (sum l_c).
// grid (24, 24).  Thread t: q=t>>2, feats (t&3)*16..+15.
// ---------------------------------------------------------------------------
__global__ void combine(const unsigned short* __restrict__ Opart,
                        const float* __restrict__ ml,
                        unsigned short* __restrict__ Z)
{
    const int qt = blockIdx.x + 8, bh = blockIdx.y;
    const int b = bh / H_, h = bh - b * H_;
    const int g = qt >> 3, r7 = qt & 7;
    const int nc = g + 1;
    const int base = bh * NCHUNK_ + qt + 4 * g * (g - 1) + r7 * g;

    const int t = threadIdx.x;
    const int q = t >> 2, fs = (t & 3) * 16;

    float L = 0.f;
    for (int c = 0; c < nc; c++)
        L += ml[(size_t)(base + c) * 128 + 64 + q];
    const float invL = 1.0f / L;

    float o[16] = {};
    for (int c = 0; c < nc; c++) {
        const unsigned short* op =
            Opart + (size_t)(base + c) * 4096 + q * 64 + fs;
        float f[8];
        b82f(ld16u(op), f);
#pragma unroll
        for (int j = 0; j < 8; j++) o[j] += f[j];
        b82f(ld16u(op + 8), f);
#pragma unroll
        for (int j = 0; j < 8; j++) o[8 + j] += f[j];
    }

    unsigned short* zp =
        Z + ((size_t)b * S_ + qt * 64 + q) * (H_ * M_) + h * M_ + fs;
    uint4 u0, u1;
    u0.x = pack2(o[0]*invL,  o[1]*invL);  u0.y = pack2(o[2]*invL,  o[3]*invL);
    u0.z = pack2(o[4]*invL,  o[5]*invL);  u0.w = pack2(o[6]*invL,  o[7]*invL);
    u1.x = pack2(o[8]*invL,  o[9]*invL);  u1.y = pack2(o[10]*invL, o[11]*invL);
    u1.z = pack2(o[12]*invL, o[13]*invL); u1.w = pack2(o[14]*invL, o[15]*invL);
    st16(zp, u0);
    st16(zp + 8, u1);
}

// ---------------------------------------------------------------------------
// Output projection GEMM (single-buffer async staging).
// Tile 64x128 -> grid (64,6) = 384 blocks = 1.5/CU (R9 balance fix).
// LDS 24KB; both half-blocks co-resident.
// ---------------------------------------------------------------------------
__global__ __launch_bounds__(256, 2) void oproj_gemm(
    const unsigned short* __restrict__ Zin,   // [4096][768] bf16
    const unsigned short* __restrict__ WOT,   // [768][768] bf16 (B^T)
    const float* __restrict__ bO,             // [768] fp32
    float* __restrict__ out)                  // [4096][768] fp32
{
    const int row0 = blockIdx.x * 64;
    const int col0 = blockIdx.y * 128;
    const int t = threadIdx.x;
    const int w = t >> 6, lane = t & 63, quad = lane >> 4, l16 = lane & 15;
    const int wrow0 = (w & 1) * 32, wcol0 = (w >> 1) * 64;

    __shared__ unsigned short Alds[64 * 64];
    __shared__ unsigned short Blds[128 * 64];

    f32x4 acc[2][4] = {};

    const unsigned short* asrc[2];
    const unsigned short* bsrc[4];
    int ldsoffA[2], ldsoffB[4];
#pragma unroll
    for (int q = 0; q < 2; q++) {
        const int cq = w * 128 + q * 64 + lane;
        const int row = cq >> 3, c = cq & 7;
        const int cs = c ^ (row & 7);
        asrc[q] = Zin + (size_t)(row0 + row) * D_ + cs * 8;
        ldsoffA[q] = (w * 128 + q * 64) * 8;
    }
#pragma unroll
    for (int q = 0; q < 4; q++) {
        const int cq = w * 256 + q * 64 + lane;
        const int row = cq >> 3, c = cq & 7;
        const int cs = c ^ (row & 7);
        bsrc[q] = WOT + (size_t)(col0 + row) * D_ + cs * 8;
        ldsoffB[q] = (w * 256 + q * 64) * 8;
    }
    const int swz = (l16 & 7);

    for (int k0 = 0; k0 < D_; k0 += 64) {
#pragma unroll
        for (int q = 0; q < 2; q++) async16(asrc[q] + k0, Alds + ldsoffA[q]);
#pragma unroll
        for (int q = 0; q < 4; q++) async16(bsrc[q] + k0, Blds + ldsoffB[q]);
        __syncthreads();

        bf16x8 af[2][2], bfm[4][2];
#pragma unroll
        for (int rt = 0; rt < 2; rt++) {
            const int row = wrow0 + rt * 16 + l16;
#pragma unroll
            for (int hh = 0; hh < 2; hh++)
                af[rt][hh] = ld16(&Alds[row * 64 + ((hh * 4 + quad) ^ swz) * 8]);
        }
#pragma unroll
        for (int st = 0; st < 4; st++) {
            const int row = wcol0 + st * 16 + l16;
#pragma unroll
            for (int hh = 0; hh < 2; hh++)
                bfm[st][hh] = ld16(&Blds[row * 64 + ((hh * 4 + quad) ^ swz) * 8]);
        }
#pragma unroll
        for (int rt = 0; rt < 2; rt++)
#pragma unroll
            for (int st = 0; st < 4; st++) {
                acc[rt][st] = __builtin_amdgcn_mfma_f32_16x16x32_bf16(
                    af[rt][0], bfm[st][0], acc[rt][st], 0, 0, 0);
                acc[rt][st] = __builtin_amdgcn_mfma_f32_16x16x32_bf16(
                    af[rt][1], bfm[st][1], acc[rt][st], 0, 0, 0);
            }
        __syncthreads();
    }

#pragma unroll
    for (int st = 0; st < 4; st++) {
        const int c = col0 + wcol0 + st * 16 + l16;
        const float bval = bO[c];
#pragma unroll
        for (int rt = 0; rt < 2; rt++)
#pragma unroll
            for (int rr = 0; rr < 4; rr++) {
                const int R = row0 + wrow0 + rt * 16 + quad * 4 + rr;
                out[(size_t)R * D_ + c] = acc[rt][st][rr] + bval;
            }
    }
}

// ---------------------------------------------------------------------------
extern "C" void kernel_launch(void* const* d_in, const int* in_sizes, int n_in,
                              void* d_out, int out_size, void* d_ws, size_t ws_size,
                              hipStream_t stream)
{
    const float* x  = (const float*)d_in[0];
    const float* WQ = (const float*)d_in[1];
    const float* bQ = (const float*)d_in[2];
    const float* WK = (const float*)d_in[3];
    const float* bK = (const float*)d_in[4];
    const float* WV = (const float*)d_in[5];
    const float* bV = (const float*)d_in[6];
    const float* WO = (const float*)d_in[7];
    const float* bO = (const float*)d_in[8];
    float* out = (float*)d_out;

    const size_t n = (size_t)B_ * H_ * S_ * M_;     // 3,145,728 elems
    unsigned short* q_ws  = (unsigned short*)d_ws;  // [B,H,S,M] bf16 (scaled)
    unsigned short* k_ws  = q_ws + n;               // [B,H,S,M] (block-swizzled)
    unsigned short* vt_ws = k_ws + n;               // [B,H,16,M,128] tiled image
    unsigned short* z_ws  = vt_ws + n;              // [B,S,H*M]
    unsigned short* WT    = z_ws + n;               // [2304][768]
    unsigned short* WOT   = WT + (size_t)NQKV_ * D_;// [768][768]
    unsigned short* xb    = WOT + (size_t)D_ * D_;  // [4096][768]
    unsigned short* Opart = xb + (size_t)BS_ * D_;  // [1920][4096] bf16
    float* mlbuf = (float*)(Opart + (size_t)TOTCHUNK_ * 4096); // [1920][128]

    prep<<<dim3(1056), 256, 0, stream>>>(WQ, WK, WV, WO, x, WT, WOT, xb);
    qkv_gemm<<<dim3(BS_ / 128, NQKV_ / 96), 256, 0, stream>>>(
        xb, WT, bQ, bK, bV, q_ws, k_ws, vt_ws);
    attn_split<<<dim3(NCHUNK_, B_ * H_), 256, 0, stream>>>(
        q_ws, k_ws, vt_ws, Opart, mlbuf, z_ws);
    combine<<<dim3(S_ / 64 - 8, B_ * H_), 256, 0, stream>>>(
        Opart, mlbuf, z_ws);
    oproj_gemm<<<dim3(BS_ / 64, D_ / 128), 256, 0, stream>>>(
        z_ws, WOT, bO, out);
}

// Round 11
// 149.856 us; speedup vs baseline: 1.0186x; 1.0186x over previous
//
#include <hip/hip_runtime.h>
#include <hip/hip_bf16.h>
#include <cstdint>
#include <cstddef>

#define B_ 2
#define S_ 2048
#define D_ 768
#define H_ 12
#define M_ 64
#define BS_ (B_ * S_)
#define NQKV_ 2304            // 3 * 768 packed output columns
#define NCHUNK_ 80            // compact chunks per bh (sum of ceil((qt+1)/8))
#define TOTCHUNK_ (24 * NCHUNK_)   // 1920
#define QSCALE 0.18033688011f // 0.125 * log2(e): softmax done in exp2 space

typedef __attribute__((ext_vector_type(8))) short bf16x8;
typedef __attribute__((ext_vector_type(4))) short bf16x4;
typedef __attribute__((ext_vector_type(4))) float f32x4;

__device__ __forceinline__ unsigned short f2bu(float f) {
    __hip_bfloat16 h = __float2bfloat16(f);   // RNE
    unsigned short u;
    __builtin_memcpy(&u, &h, 2);
    return u;
}
__device__ __forceinline__ unsigned pack2(float a, float b) {
    return (unsigned)f2bu(a) | ((unsigned)f2bu(b) << 16);
}

// Alias-safe vector load/store (memcpy => char semantics, still b128 ops).
__device__ __forceinline__ bf16x8 ld16(const unsigned short* p) {
    p = (const unsigned short*)__builtin_assume_aligned(p, 16);
    bf16x8 v; __builtin_memcpy(&v, p, 16); return v;
}
__device__ __forceinline__ bf16x4 ld8(const unsigned short* p) {
    p = (const unsigned short*)__builtin_assume_aligned(p, 8);
    bf16x4 v; __builtin_memcpy(&v, p, 8); return v;
}
__device__ __forceinline__ uint4 ld16u(const unsigned short* p) {
    p = (const unsigned short*)__builtin_assume_aligned(p, 16);
    uint4 v; __builtin_memcpy(&v, p, 16); return v;
}
__device__ __forceinline__ void st16(unsigned short* p, uint4 v) {
    p = (unsigned short*)__builtin_assume_aligned(p, 16);
    __builtin_memcpy(p, &v, 16);
}
__device__ __forceinline__ void st8(unsigned short* p, uint2 v) {
    p = (unsigned short*)__builtin_assume_aligned(p, 8);
    __builtin_memcpy(p, &v, 8);
}
__device__ __forceinline__ float4 ldf4(const float* p) {
    p = (const float*)__builtin_assume_aligned(p, 16);
    float4 v; __builtin_memcpy(&v, p, 16); return v;
}
// async global->LDS, 16B per lane; lds base must be wave-uniform.
__device__ __forceinline__ void async16(const unsigned short* g, unsigned short* l) {
    __builtin_amdgcn_global_load_lds(
        (const __attribute__((address_space(1))) void*)g,
        (__attribute__((address_space(3))) void*)l, 16, 0, 0);
}
__device__ __forceinline__ void b82f(uint4 u, float* o) {
    o[0] = __uint_as_float(u.x << 16); o[1] = __uint_as_float(u.x & 0xffff0000u);
    o[2] = __uint_as_float(u.y << 16); o[3] = __uint_as_float(u.y & 0xffff0000u);
    o[4] = __uint_as_float(u.z << 16); o[5] = __uint_as_float(u.z & 0xffff0000u);
    o[6] = __uint_as_float(u.w << 16); o[7] = __uint_as_float(u.w & 0xffff0000u);
}

#define NEG_BIG (-3.0e38f)

// ---------------------------------------------------------------------------
// prep: fused weight packing + x conversion.
// ---------------------------------------------------------------------------
__global__ void prep(const float* __restrict__ WQ, const float* __restrict__ WK,
                     const float* __restrict__ WV, const float* __restrict__ WO,
                     const float* __restrict__ x,
                     unsigned short* __restrict__ WT,
                     unsigned short* __restrict__ WOT,
                     unsigned short* __restrict__ xb)
{
    const int bx = blockIdx.x;
    if (bx < 216) {
        const int xx = bx % 9, yy = bx / 9;
        const int c  = xx * 256 + threadIdx.x;   // 0..2303
        const int k0 = yy * 32;
        const int which = c / D_;
        const int r = c - which * D_;
        const int h = r >> 6, m = r & 63;
        const float* Wsel = (which == 0) ? WQ : (which == 1) ? WK : WV;
        const float* src = Wsel + (size_t)h * D_ * M_ + m;
        unsigned short* dst = WT + (size_t)c * D_ + k0;
        for (int i = 0; i < 32; i += 8) {
            float wv[8];
#pragma unroll
            for (int j = 0; j < 8; j++) wv[j] = src[(size_t)(k0 + i + j) * M_];
            uint4 pu;
            pu.x = pack2(wv[0], wv[1]); pu.y = pack2(wv[2], wv[3]);
            pu.z = pack2(wv[4], wv[5]); pu.w = pack2(wv[6], wv[7]);
            st16(dst + i, pu);
        }
    } else if (bx < 288) {
        const int b2 = bx - 216;
        const int xx = b2 % 3, yy = b2 / 3;
        const int c  = xx * 256 + threadIdx.x;   // output row d, 0..767
        const int k0 = yy * 32;
        unsigned short* dst = WOT + (size_t)c * D_ + k0;
        for (int i = 0; i < 32; i += 8) {
            float wv[8];
#pragma unroll
            for (int j = 0; j < 8; j++) wv[j] = WO[(size_t)(k0 + i + j) * D_ + c];
            uint4 pu;
            pu.x = pack2(wv[0], wv[1]); pu.y = pack2(wv[2], wv[3]);
            pu.z = pack2(wv[4], wv[5]); pu.w = pack2(wv[6], wv[7]);
            st16(dst + i, pu);
        }
    } else {
        const size_t i = ((size_t)(bx - 288) * 256 + threadIdx.x) * 16;
#pragma unroll
        for (int p = 0; p < 2; p++) {
            float4 a0 = ldf4(x + i + p * 8), a1 = ldf4(x + i + p * 8 + 4);
            uint4 u;
            u.x = pack2(a0.x, a0.y); u.y = pack2(a0.z, a0.w);
            u.z = pack2(a1.x, a1.y); u.w = pack2(a1.z, a1.w);
            st16(xb + i + p * 8, u);
        }
    }
}

// ---------------------------------------------------------------------------
// QKV projection GEMM (single-buffer async staging).  Tile 128x96 ->
// grid (32,24) = 768 blocks = EXACTLY 3 blocks/CU (R9 imbalance fix).
// LDS 28KB, 3 blocks co-resident.
// Q pre-scaled by 0.125*log2(e)  (softmax runs in exp2 space downstream).
// K and V are emitted in PRE-SWIZZLED physical image layouts so attn_split
// can stage them with pure linear global_load_lds:
//   K: [bh][s][phys 16B block p] holds logical block p^(s&7)
//   V: [bh][tile=s>>7][m][32x 8B granules], pair pp = pl^((m>>1)&7),
//      8B half = (gl&1)^(m&1)  (odd feats half-swapped)
// ---------------------------------------------------------------------------
__global__ __launch_bounds__(256, 2) void qkv_gemm(
    const unsigned short* __restrict__ xb,    // [4096][768] bf16
    const unsigned short* __restrict__ WT,    // [2304][768] bf16
    const float* __restrict__ bQ, const float* __restrict__ bK,
    const float* __restrict__ bV,
    unsigned short* __restrict__ qo, unsigned short* __restrict__ ko,
    unsigned short* __restrict__ vt)
{
    const int row0 = blockIdx.x * 128;
    const int col0 = blockIdx.y * 96;
    const int t = threadIdx.x;
    const int w = t >> 6, lane = t & 63, quad = lane >> 4, l16 = lane & 15;
    const int wrow0 = (w & 1) * 64, wcol0 = (w >> 1) * 48;

    __shared__ unsigned short Alds[128 * 64];   // unpadded, swizzled
    __shared__ unsigned short Blds[96 * 64];

    f32x4 acc[4][3] = {};

    const unsigned short* asrc[4];
    const unsigned short* bsrc[3];
    int ldsoffA[4], ldsoffB[3];
#pragma unroll
    for (int q = 0; q < 4; q++) {
        const int cq = w * 256 + q * 64 + lane;
        const int row = cq >> 3, c = cq & 7;
        const int cs = c ^ (row & 7);
        asrc[q] = xb + (size_t)(row0 + row) * D_ + cs * 8;
        ldsoffA[q] = (w * 256 + q * 64) * 8;   // wave-uniform
    }
#pragma unroll
    for (int q = 0; q < 3; q++) {
        const int cq = w * 192 + q * 64 + lane;
        const int row = cq >> 3, c = cq & 7;
        const int cs = c ^ (row & 7);
        bsrc[q] = WT + (size_t)(col0 + row) * D_ + cs * 8;
        ldsoffB[q] = (w * 192 + q * 64) * 8;   // wave-uniform
    }
    const int swz = (l16 & 7);

    for (int k0 = 0; k0 < D_; k0 += 64) {
#pragma unroll
        for (int q = 0; q < 4; q++) async16(asrc[q] + k0, Alds + ldsoffA[q]);
#pragma unroll
        for (int q = 0; q < 3; q++) async16(bsrc[q] + k0, Blds + ldsoffB[q]);
        __syncthreads();   // drains vmcnt -> DMA landed

        bf16x8 af[4][2], bfm[3][2];
#pragma unroll
        for (int rt = 0; rt < 4; rt++) {
            const int row = wrow0 + rt * 16 + l16;
#pragma unroll
            for (int hh = 0; hh < 2; hh++)
                af[rt][hh] = ld16(&Alds[row * 64 + ((hh * 4 + quad) ^ swz) * 8]);
        }
#pragma unroll
        for (int st = 0; st < 3; st++) {
            const int row = wcol0 + st * 16 + l16;
#pragma unroll
            for (int hh = 0; hh < 2; hh++)
                bfm[st][hh] = ld16(&Blds[row * 64 + ((hh * 4 + quad) ^ swz) * 8]);
        }
#pragma unroll
        for (int rt = 0; rt < 4; rt++)
#pragma unroll
            for (int st = 0; st < 3; st++) {
                acc[rt][st] = __builtin_amdgcn_mfma_f32_16x16x32_bf16(
                    af[rt][0], bfm[st][0], acc[rt][st], 0, 0, 0);
                acc[rt][st] = __builtin_amdgcn_mfma_f32_16x16x32_bf16(
                    af[rt][1], bfm[st][1], acc[rt][st], 0, 0, 0);
            }
        __syncthreads();
    }

    const int which = col0 / D_;            // 96*8 = 768: exact boundaries
    const int colin = col0 - which * D_;

    if (which == 0) {
#pragma unroll
        for (int st = 0; st < 3; st++) {
            const int cl = colin + wcol0 + st * 16 + l16;
            const int h = cl >> 6, m = cl & 63;
            const float bval = bQ[cl];
#pragma unroll
            for (int rt = 0; rt < 4; rt++)
#pragma unroll
                for (int rr = 0; rr < 4; rr++) {
                    const int R = row0 + wrow0 + rt * 16 + quad * 4 + rr;
                    const int bb = R >> 11, s = R & (S_ - 1);
                    qo[(((size_t)bb * H_ + h) * S_ + s) * M_ + m] =
                        f2bu((acc[rt][st][rr] + bval) * QSCALE);
                }
        }
    } else if (which == 1) {
        // K: pre-swizzled 16B blocks: elem (s,m) -> block (m>>3)^(s&7), inner m&7
#pragma unroll
        for (int st = 0; st < 3; st++) {
            const int cl = colin + wcol0 + st * 16 + l16;
            const int h = cl >> 6, m = cl & 63;
            const int blk = m >> 3, inn = m & 7;
            const float bval = bK[cl];
#pragma unroll
            for (int rt = 0; rt < 4; rt++)
#pragma unroll
                for (int rr = 0; rr < 4; rr++) {
                    const int R = row0 + wrow0 + rt * 16 + quad * 4 + rr;
                    const int bb = R >> 11, s = R & (S_ - 1);
                    ko[(((size_t)bb * H_ + h) * S_ + s) * M_ +
                       ((blk ^ (s & 7)) << 3) + inn] =
                        f2bu(acc[rt][st][rr] + bval);
                }
        }
    } else {
        // V: tiled-swizzled image [bh][tile][m][granules]; one st8 = one granule.
#pragma unroll
        for (int st = 0; st < 3; st++) {
            const int cl = colin + wcol0 + st * 16 + l16;
            const int h = cl >> 6, m = cl & 63;
            const float bval = bV[cl];
#pragma unroll
            for (int rt = 0; rt < 4; rt++) {
                const int R0 = row0 + wrow0 + rt * 16 + quad * 4;
                const int bb = R0 >> 11, s0 = R0 & (S_ - 1);
                const int tile = s0 >> 7;
                const int gl = (s0 & 127) >> 2;        // logical granule
                const int pl = gl >> 1, hi = gl & 1;
                const int pp = pl ^ ((m >> 1) & 7);    // phys 16B pair
                const int half = hi ^ (m & 1);         // odd feat: swap halves
                uint2 v;
                v.x = pack2(acc[rt][st][0] + bval, acc[rt][st][1] + bval);
                v.y = pack2(acc[rt][st][2] + bval, acc[rt][st][3] + bval);
                st8(&vt[(((size_t)bb * H_ + h) * 16 + tile) * (M_ * 128)
                        + m * 128 + (pp * 2 + half) * 4], v);
            }
        }
    }
}

// ---------------------------------------------------------------------------
// Split-K causal flash attention, transposed compute space, exp2 softmax
// with STATIC zero max.  PV uses K=16 MFMA so the packed QK output registers
// ARE the B-fragment -- no P LDS round-trip.  Best-measured structure:
// single 32KB buffer, pure linear global_load_lds from PRE-SWIZZLED K/V,
// 4 blocks/CU of cross-block TLP hides the DMA drain.
//
// Round 11: R10's setprio REMOVED (misapplied T5: our 4-wave blocks are
// barrier-lockstep == the m190-negative GEMM regime, not m191's
// independent-phase attn; boosting the MFMA wave delayed co-resident
// blocks' DMA issue).  KEPT: nc==1 chunks (qt<8) normalize and write Z
// directly, skipping Opart+ml (pure traffic reduction; absmax improved).
// grid (80, 24).
// ---------------------------------------------------------------------------
__global__ __launch_bounds__(256, 2) void attn_split(
    const unsigned short* __restrict__ Q,   // [B,H,S,M] bf16 (exp2-scaled)
    const unsigned short* __restrict__ Kin, // [B,H,S,M] bf16 (block-swizzled)
    const unsigned short* __restrict__ Vt,  // [B,H,16,M,128] bf16 (tiled image)
    unsigned short* __restrict__ Opart,     // [1920][64][64] bf16
    float* __restrict__ ml,                 // [1920][128] fp32 (l in 2nd half)
    unsigned short* __restrict__ Z)         // [B,S,H*M] bf16 (nc==1 direct)
{
    // XCD-locality + descending-work remap (dispatch order is x-major).
    const int flat = blockIdx.y * NCHUNK_ + blockIdx.x;
    const int bh = flat % 24;                    // XCD = flat%8 = bh%8
    const int xx = (NCHUNK_ - 1) - flat / 24;    // big chunks dispatched first

    int qt, c, nc;
    if (xx < 8)       { qt = xx; c = 0; nc = 1; }
    else if (xx < 24) { int u = xx - 8;  qt = 8  + (u >> 1); c = u & 1;  nc = 2; }
    else if (xx < 48) { int u = xx - 24; qt = 16 + u / 3;    c = u % 3;  nc = 3; }
    else              { int u = xx - 48; qt = 24 + (u >> 2); c = u & 3;  nc = 4; }

    const int ci     = bh * NCHUNK_ + xx;
    const int kbeg   = c * 512;
    const int keyend = min((qt + 1) * 64, kbeg + 512);
    const int iters  = (keyend - kbeg + 127) >> 7;
    const bool lastchunk = (c == nc - 1);

    const int t = threadIdx.x;
    const int wave = t >> 6, lane = t & 63, quad = lane >> 4, l16 = lane & 15;

    const unsigned short* Qb  = Q   + ((size_t)bh * S_ + qt * 64) * M_;
    const unsigned short* Kb  = Kin + (size_t)bh * S_ * M_;
    const unsigned short* Vb  = Vt  + (size_t)bh * M_ * S_;   // tiled image

    // Physical (pre-swizzled) tiles, staged linearly; 32 KB total.
    __shared__ unsigned short Klds[128 * 64];
    __shared__ unsigned short Vlds[64 * 128];

    bf16x8 qf[2];   // B-frag of Q^T
    {
        const unsigned short* qrow = Qb + (size_t)(wave * 16 + l16) * M_;
        qf[0] = ld16(qrow + quad * 8);
        qf[1] = ld16(qrow + 32 + quad * 8);
    }

    // lane-constant swizzled read offsets, hoisted out of all loops
    const int ksw = l16 & 7;
    const int ko0 = (quad ^ ksw) * 8;          // K block quad   (feat 0..31)
    const int ko1 = ((quad + 4) ^ ksw) * 8;    // K block quad+4 (feat 32..63)
    int voff[8];                               // V granule addr per key-block
#pragma unroll
    for (int st = 0; st < 8; st++)
        voff[st] = l16 * 128 + (quad ^ (l16 & 3)) * 4
                 + ((st ^ ((l16 >> 2) & 3)) << 4);

    const int wdst = wave * 64 * 8;            // wave-uniform LDS base (ushorts)

    f32x4 o_acc[4] = {};
    float lrow = 0.f;   // per-lane partial sum of P (static max = 0)

    for (int it = 0; it < iters; it++) {
        __syncthreads();   // prior iteration's LDS reads complete
        const int key0 = kbeg + it * 128;
        const unsigned short* kt = Kb + (size_t)key0 * M_;
        const unsigned short* vtile = Vb + (size_t)(key0 >> 7) * (M_ * 128);
#pragma unroll
        for (int q = 0; q < 4; q++)
            async16(kt + (size_t)(q * 256 + t) * 8, Klds + q * 2048 + wdst);
#pragma unroll
        for (int q = 0; q < 4; q++)
            async16(vtile + (size_t)(q * 256 + t) * 8, Vlds + q * 2048 + wdst);
        __syncthreads();   // drains vmcnt -> DMA landed

        // S^T = K Q^T over 128 keys (8 row strips of 16 keys)
        f32x4 s_acc[8];
#pragma unroll
        for (int st = 0; st < 8; st++) {
            f32x4 z4 = {0.f, 0.f, 0.f, 0.f};
            const unsigned short* krow = &Klds[(st * 16 + l16) * 64];
            bf16x8 k0 = ld16(krow + ko0);
            bf16x8 k1 = ld16(krow + ko1);
            z4 = __builtin_amdgcn_mfma_f32_16x16x32_bf16(k0, qf[0], z4, 0, 0, 0);
            z4 = __builtin_amdgcn_mfma_f32_16x16x32_bf16(k1, qf[1], z4, 0, 0, 0);
            s_acc[st] = z4;   // s_acc[st][r] = S^T[key=st*16+quad*4+r][q=l16]
        }

        if (lastchunk && it == iters - 1) {
            const int keyq = kbeg + it * 128 + quad * 4;
            const int qg = qt * 64 + wave * 16 + l16;
#pragma unroll
            for (int st = 0; st < 8; st++)
#pragma unroll
                for (int r = 0; r < 4; r++)
                    if (keyq + st * 16 + r > qg)
                        s_acc[st][r] = -1e30f;
        }

        // P = exp2(S) (no max subtraction), pack strips directly into the
        // K=16 MFMA B-fragment layout (B[k=quad*4+j][n=l16] == C layout!)
        bf16x4 pkv[8];
#pragma unroll
        for (int st = 0; st < 8; st++) {
            float p0 = exp2f(s_acc[st][0]);
            float p1 = exp2f(s_acc[st][1]);
            float p2 = exp2f(s_acc[st][2]);
            float p3 = exp2f(s_acc[st][3]);
            lrow += (p0 + p1) + (p2 + p3);
            uint2 u;
            u.x = pack2(p0, p1);
            u.y = pack2(p2, p3);
            __builtin_memcpy(&pkv[st], &u, 8);
        }

        // O^T += V^T P^T via 16x16x16 MFMA (P straight from registers)
#pragma unroll
        for (int stf = 0; stf < 4; stf++) {
#pragma unroll
            for (int st = 0; st < 8; st++) {
                bf16x4 va = ld8(&Vlds[stf * 2048 + voff[st]]);
                o_acc[stf] = __builtin_amdgcn_mfma_f32_16x16x16bf16_1k(
                    va, pkv[st], o_acc[stf], 0, 0, 0);
            }
        }
    }

    // reduce l across the 4 quads (columns are per-lane; quads partition keys)
    lrow += __shfl_xor(lrow, 16, 64);
    lrow += __shfl_xor(lrow, 32, 64);

    const int q = wave * 16 + l16;
    if (nc == 1) {
        // complete row: normalize and write Z directly (skip Opart/ml)
        const float invL = 1.0f / lrow;
        const int b = bh / H_, h = bh - b * H_;
        unsigned short* zp =
            Z + ((size_t)b * S_ + qt * 64 + q) * (H_ * M_) + h * M_;
#pragma unroll
        for (int stf = 0; stf < 4; stf++) {
            uint2 u;
            u.x = pack2(o_acc[stf][0] * invL, o_acc[stf][1] * invL);
            u.y = pack2(o_acc[stf][2] * invL, o_acc[stf][3] * invL);
            st8(&zp[stf * 16 + quad * 4], u);
        }
    } else {
        // write unnormalized partials (bf16), O^T -> [q][feat] packed stores
        unsigned short* Op = Opart + (size_t)ci * 4096;
#pragma unroll
        for (int stf = 0; stf < 4; stf++) {
            uint2 u;
            u.x = pack2(o_acc[stf][0], o_acc[stf][1]);
            u.y = pack2(o_acc[stf][2], o_acc[stf][3]);
            st8(&Op[q * 64 + stf * 16 + quad * 4], u);
        }
        if (quad == 0)
            ml[(size_t)ci * 128 + 64 + q] = lrow;
    }
}

// ---------------------------------------------------------------------------
// Combine: merge 2..4 bf16 partials per (bh, qt>=8) into Z [B,S,H*M] bf16.
// (qt<8 are written directly by attn_split.)  Static-max softmax ->
// uniform weights: z = (sum O_c) / (sum l_c).
// grid (24, 24).  Thread t: q=t>>2, feats (t&3)*16..+15.
// ---------------------------------------------------------------------------
__global__ void combine(const unsigned short* __restrict__ Opart,
                        const float* __restrict__ ml,
                        unsigned short* __restrict__ Z)
{
    const int qt = blockIdx.x + 8, bh = blockIdx.y;
    const int b = bh / H_, h = bh - b * H_;
    const int g = qt >> 3, r7 = qt & 7;
    const int nc = g + 1;
    const int base = bh * NCHUNK_ + qt + 4 * g * (g - 1) + r7 * g;

    const int t = threadIdx.x;
    const int q = t >> 2, fs = (t & 3) * 16;

    float L = 0.f;
    for (int c = 0; c < nc; c++)
        L += ml[(size_t)(base + c) * 128 + 64 + q];
    const float invL = 1.0f / L;

    float o[16] = {};
    for (int c = 0; c < nc; c++) {
        const unsigned short* op =
            Opart + (size_t)(base + c) * 4096 + q * 64 + fs;
        float f[8];
        b82f(ld16u(op), f);
#pragma unroll
        for (int j = 0; j < 8; j++) o[j] += f[j];
        b82f(ld16u(op + 8), f);
#pragma unroll
        for (int j = 0; j < 8; j++) o[8 + j] += f[j];
    }

    unsigned short* zp =
        Z + ((size_t)b * S_ + qt * 64 + q) * (H_ * M_) + h * M_ + fs;
    uint4 u0, u1;
    u0.x = pack2(o[0]*invL,  o[1]*invL);  u0.y = pack2(o[2]*invL,  o[3]*invL);
    u0.z = pack2(o[4]*invL,  o[5]*invL);  u0.w = pack2(o[6]*invL,  o[7]*invL);
    u1.x = pack2(o[8]*invL,  o[9]*invL);  u1.y = pack2(o[10]*invL, o[11]*invL);
    u1.z = pack2(o[12]*invL, o[13]*invL); u1.w = pack2(o[14]*invL, o[15]*invL);
    st16(zp, u0);
    st16(zp + 8, u1);
}

// ---------------------------------------------------------------------------
// Output projection GEMM (single-buffer async staging).
// Tile 64x128 -> grid (64,6) = 384 blocks = 1.5/CU (R9 balance fix).
// LDS 24KB; both half-blocks co-resident.
// ---------------------------------------------------------------------------
__global__ __launch_bounds__(256, 2) void oproj_gemm(
    const unsigned short* __restrict__ Zin,   // [4096][768] bf16
    const unsigned short* __restrict__ WOT,   // [768][768] bf16 (B^T)
    const float* __restrict__ bO,             // [768] fp32
    float* __restrict__ out)                  // [4096][768] fp32
{
    const int row0 = blockIdx.x * 64;
    const int col0 = blockIdx.y * 128;
    const int t = threadIdx.x;
    const int w = t >> 6, lane = t & 63, quad = lane >> 4, l16 = lane & 15;
    const int wrow0 = (w & 1) * 32, wcol0 = (w >> 1) * 64;

    __shared__ unsigned short Alds[64 * 64];
    __shared__ unsigned short Blds[128 * 64];

    f32x4 acc[2][4] = {};

    const unsigned short* asrc[2];
    const unsigned short* bsrc[4];
    int ldsoffA[2], ldsoffB[4];
#pragma unroll
    for (int q = 0; q < 2; q++) {
        const int cq = w * 128 + q * 64 + lane;
        const int row = cq >> 3, c = cq & 7;
        const int cs = c ^ (row & 7);
        asrc[q] = Zin + (size_t)(row0 + row) * D_ + cs * 8;
        ldsoffA[q] = (w * 128 + q * 64) * 8;
    }
#pragma unroll
    for (int q = 0; q < 4; q++) {
        const int cq = w * 256 + q * 64 + lane;
        const int row = cq >> 3, c = cq & 7;
        const int cs = c ^ (row & 7);
        bsrc[q] = WOT + (size_t)(col0 + row) * D_ + cs * 8;
        ldsoffB[q] = (w * 256 + q * 64) * 8;
    }
    const int swz = (l16 & 7);

    for (int k0 = 0; k0 < D_; k0 += 64) {
#pragma unroll
        for (int q = 0; q < 2; q++) async16(asrc[q] + k0, Alds + ldsoffA[q]);
#pragma unroll
        for (int q = 0; q < 4; q++) async16(bsrc[q] + k0, Blds + ldsoffB[q]);
        __syncthreads();

        bf16x8 af[2][2], bfm[4][2];
#pragma unroll
        for (int rt = 0; rt < 2; rt++) {
            const int row = wrow0 + rt * 16 + l16;
#pragma unroll
            for (int hh = 0; hh < 2; hh++)
                af[rt][hh] = ld16(&Alds[row * 64 + ((hh * 4 + quad) ^ swz) * 8]);
        }
#pragma unroll
        for (int st = 0; st < 4; st++) {
            const int row = wcol0 + st * 16 + l16;
#pragma unroll
            for (int hh = 0; hh < 2; hh++)
                bfm[st][hh] = ld16(&Blds[row * 64 + ((hh * 4 + quad) ^ swz) * 8]);
        }
#pragma unroll
        for (int rt = 0; rt < 2; rt++)
#pragma unroll
            for (int st = 0; st < 4; st++) {
                acc[rt][st] = __builtin_amdgcn_mfma_f32_16x16x32_bf16(
                    af[rt][0], bfm[st][0], acc[rt][st], 0, 0, 0);
                acc[rt][st] = __builtin_amdgcn_mfma_f32_16x16x32_bf16(
                    af[rt][1], bfm[st][1], acc[rt][st], 0, 0, 0);
            }
        __syncthreads();
    }

#pragma unroll
    for (int st = 0; st < 4; st++) {
        const int c = col0 + wcol0 + st * 16 + l16;
        const float bval = bO[c];
#pragma unroll
        for (int rt = 0; rt < 2; rt++)
#pragma unroll
            for (int rr = 0; rr < 4; rr++) {
                const int R = row0 + wrow0 + rt * 16 + quad * 4 + rr;
                out[(size_t)R * D_ + c] = acc[rt][st][rr] + bval;
            }
    }
}

// ---------------------------------------------------------------------------
extern "C" void kernel_launch(void* const* d_in, const int* in_sizes, int n_in,
                              void* d_out, int out_size, void* d_ws, size_t ws_size,
                              hipStream_t stream)
{
    const float* x  = (const float*)d_in[0];
    const float* WQ = (const float*)d_in[1];
    const float* bQ = (const float*)d_in[2];
    const float* WK = (const float*)d_in[3];
    const float* bK = (const float*)d_in[4];
    const float* WV = (const float*)d_in[5];
    const float* bV = (const float*)d_in[6];
    const float* WO = (const float*)d_in[7];
    const float* bO = (const float*)d_in[8];
    float* out = (float*)d_out;

    const size_t n = (size_t)B_ * H_ * S_ * M_;     // 3,145,728 elems
    unsigned short* q_ws  = (unsigned short*)d_ws;  // [B,H,S,M] bf16 (scaled)
    unsigned short* k_ws  = q_ws + n;               // [B,H,S,M] (block-swizzled)
    unsigned short* vt_ws = k_ws + n;               // [B,H,16,M,128] tiled image
    unsigned short* z_ws  = vt_ws + n;              // [B,S,H*M]
    unsigned short* WT    = z_ws + n;               // [2304][768]
    unsigned short* WOT   = WT + (size_t)NQKV_ * D_;// [768][768]
    unsigned short* xb    = WOT + (size_t)D_ * D_;  // [4096][768]
    unsigned short* Opart = xb + (size_t)BS_ * D_;  // [1920][4096] bf16
    float* mlbuf = (float*)(Opart + (size_t)TOTCHUNK_ * 4096); // [1920][128]

    prep<<<dim3(1056), 256, 0, stream>>>(WQ, WK, WV, WO, x, WT, WOT, xb);
    qkv_gemm<<<dim3(BS_ / 128, NQKV_ / 96), 256, 0, stream>>>(
        xb, WT, bQ, bK, bV, q_ws, k_ws, vt_ws);
    attn_split<<<dim3(NCHUNK_, B_ * H_), 256, 0, stream>>>(
        q_ws, k_ws, vt_ws, Opart, mlbuf, z_ws);
    combine<<<dim3(S_ / 64 - 8, B_ * H_), 256, 0, stream>>>(
        Opart, mlbuf, z_ws);
    oproj_gemm<<<dim3(BS_ / 64, D_ / 128), 256, 0, stream>>>(
        z_ws, WOT, bO, out);
}